// Round 1
// baseline (4078.884 us; speedup 1.0000x reference)
//
#include <hip/hip_runtime.h>

#define D 128

// ---------------- degree count + inverse ----------------
__global__ __launch_bounds__(256) void deg_count_kernel(const int* __restrict__ dst,
                                                        float* __restrict__ deg, int nE) {
    int e = blockIdx.x * 256 + threadIdx.x;
    if (e < nE) atomicAdd(&deg[dst[e]], 1.0f);
}

__global__ __launch_bounds__(256) void deg_inv_kernel(float* __restrict__ deg, int n) {
    int i = blockIdx.x * 256 + threadIdx.x;
    if (i < n) deg[i] = 1.0f / fmaxf(deg[i], 1.0f);
}

// ---------------- dual GEMM: out = x@Ws + bs + bn ; hN = x@Wn ----------------
// 256 threads: t<128 -> column t of Ws (writes out), t>=128 -> column t-128 of Wn (writes hN).
// ROWS rows of x staged in LDS per block; W streamed from global (64KB each, L1/L2-resident).
template <int ROWS>
__global__ __launch_bounds__(256) void gemm_kernel(const float* __restrict__ x,
                                                   const float* __restrict__ Ws,
                                                   const float* __restrict__ bs,
                                                   const float* __restrict__ Wn,
                                                   const float* __restrict__ bn,
                                                   float* __restrict__ outb,
                                                   float* __restrict__ hN, int n) {
    __shared__ float xs[ROWS][D + 4];
    const int row0 = blockIdx.x * ROWS;
    const int t = threadIdx.x;

    // stage ROWS x 128 f32 tile (float4 loads)
    for (int i = t; i < ROWS * (D / 4); i += 256) {
        int r = i / (D / 4);
        int cc = (i - r * (D / 4)) * 4;
        int gr = row0 + r;
        float4 v = make_float4(0.f, 0.f, 0.f, 0.f);
        if (gr < n) v = *reinterpret_cast<const float4*>(x + (size_t)gr * D + cc);
        *reinterpret_cast<float4*>(&xs[r][cc]) = v;
    }
    __syncthreads();

    const float* __restrict__ W = (t < D) ? Ws : Wn;
    const int c = t & (D - 1);

    float acc[ROWS];
#pragma unroll
    for (int r = 0; r < ROWS; ++r) acc[r] = 0.f;

    for (int k = 0; k < D; k += 4) {
        float4 xv[ROWS];
#pragma unroll
        for (int r = 0; r < ROWS; ++r)
            xv[r] = *reinterpret_cast<const float4*>(&xs[r][k]);
#pragma unroll
        for (int kk = 0; kk < 4; ++kk) {
            float w = W[(k + kk) * D + c];
#pragma unroll
            for (int r = 0; r < ROWS; ++r) {
                float xval = (kk == 0) ? xv[r].x : (kk == 1) ? xv[r].y
                           : (kk == 2) ? xv[r].z : xv[r].w;
                acc[r] = fmaf(xval, w, acc[r]);
            }
        }
    }

    const bool isS = (t < D);
    const float bias = isS ? (bs[c] + bn[c]) : 0.f;
    float* __restrict__ dstp = isS ? outb : hN;
#pragma unroll
    for (int r = 0; r < ROWS; ++r) {
        int gr = row0 + r;
        if (gr < n) dstp[(size_t)gr * D + c] = acc[r] + bias;
    }
}

// ---------------- edge scatter: out[dst] += hN[src] * degInv[dst] ----------------
__global__ __launch_bounds__(256) void scatter_kernel(const int* __restrict__ src,
                                                      const int* __restrict__ dst,
                                                      const float* __restrict__ hN,
                                                      const float* __restrict__ degInv,
                                                      float* __restrict__ out, int nE) {
    int tid = blockIdx.x * 256 + threadIdx.x;
    int e = tid >> 7;        // 128 threads (one per channel) per edge
    int c = tid & (D - 1);
    if (e < nE) {
        int s = src[e];
        int d = dst[e];
        float scale = degInv[d];
        float v = hN[(size_t)s * D + c] * scale;
        atomicAdd(&out[(size_t)d * D + c], v);
    }
}

// ---------------- relu ----------------
__global__ __launch_bounds__(256) void relu_kernel(float* __restrict__ out, size_t nElem) {
    size_t n4 = nElem / 4;
    float4* p = reinterpret_cast<float4*>(out);
    for (size_t i = (size_t)blockIdx.x * 256 + threadIdx.x; i < n4;
         i += (size_t)gridDim.x * 256) {
        float4 v = p[i];
        v.x = fmaxf(v.x, 0.f);
        v.y = fmaxf(v.y, 0.f);
        v.z = fmaxf(v.z, 0.f);
        v.w = fmaxf(v.w, 0.f);
        p[i] = v;
    }
}

extern "C" void kernel_launch(void* const* d_in, const int* in_sizes, int n_in,
                              void* d_out, int out_size, void* d_ws, size_t ws_size,
                              hipStream_t stream) {
    const float* x  = (const float*)d_in[0];
    const int*   ei = (const int*)d_in[1];
    const float* Ws = (const float*)d_in[2];
    const float* bs = (const float*)d_in[3];
    const float* Wn = (const float*)d_in[4];
    const float* bn = (const float*)d_in[5];
    float* out = (float*)d_out;

    const int n  = in_sizes[0] / D;   // 100000
    const int nE = in_sizes[1] / 2;   // 640000
    const int* src = ei;
    const int* dst = ei + nE;

    float* hN  = (float*)d_ws;              // n*D f32  (51.2 MB)
    float* deg = hN + (size_t)n * D;        // n   f32  (0.4 MB)

    hipMemsetAsync(deg, 0, (size_t)n * sizeof(float), stream);
    deg_count_kernel<<<(nE + 255) / 256, 256, 0, stream>>>(dst, deg, nE);
    deg_inv_kernel<<<(n + 255) / 256, 256, 0, stream>>>(deg, n);
    gemm_kernel<8><<<(n + 7) / 8, 256, 0, stream>>>(x, Ws, bs, Wn, bn, out, hN, n);
    scatter_kernel<<<(int)(((size_t)nE * D + 255) / 256), 256, 0, stream>>>(src, dst, hN, deg,
                                                                            out, nE);
    relu_kernel<<<2048, 256, 0, stream>>>(out, (size_t)n * D);
}

// Round 2
// 648.837 us; speedup vs baseline: 6.2864x; 6.2864x over previous
//
#include <hip/hip_runtime.h>

#define D 128

// ---------------- degree count + inverse ----------------
__global__ __launch_bounds__(256) void deg_count_kernel(const int* __restrict__ dst,
                                                        float* __restrict__ deg, int nE) {
    int e = blockIdx.x * 256 + threadIdx.x;
    if (e < nE) atomicAdd(&deg[dst[e]], 1.0f);
}

__global__ __launch_bounds__(256) void deg_inv_kernel(float* __restrict__ deg, int n) {
    int i = blockIdx.x * 256 + threadIdx.x;
    if (i < n) deg[i] = 1.0f / fmaxf(deg[i], 1.0f);
}

// ---------------- dual GEMM, row-per-thread, scalar-broadcast weights ----------------
// Thread r keeps its x-row in 32 float4 registers. Weight address W[k*D+c0+j] is
// wave-uniform -> s_load broadcast (v_fma v,s,v,v). Chunk loop unroll 1 bounds VGPRs;
// k-loop fully unrolled so xr[] indexing is compile-time constant (no scratch).
__global__ __launch_bounds__(128) void gemm_rows_kernel(const float* __restrict__ x,
                                                        const float* __restrict__ Ws,
                                                        const float* __restrict__ bs,
                                                        const float* __restrict__ Wn,
                                                        const float* __restrict__ bn,
                                                        float* __restrict__ outb,
                                                        float* __restrict__ hN, int n) {
    const int r = blockIdx.x * 128 + threadIdx.x;
    if (r >= n) return;  // no barriers in this kernel -> safe

    float4 xr[D / 4];
    const float4* __restrict__ xp = reinterpret_cast<const float4*>(x + (size_t)r * D);
#pragma unroll
    for (int i = 0; i < D / 4; ++i) xr[i] = xp[i];

    const size_t rb = (size_t)r * D;

    // ---- half 0: out = x @ Ws + (bs + bn) ----
#pragma unroll 1
    for (int c0 = 0; c0 < D; c0 += 8) {
        float acc[8];
#pragma unroll
        for (int j = 0; j < 8; ++j) acc[j] = 0.f;
#pragma unroll
        for (int k = 0; k < D; ++k) {
            float4 q = xr[k >> 2];
            float xv = ((k & 3) == 0) ? q.x : ((k & 3) == 1) ? q.y
                     : ((k & 3) == 2) ? q.z : q.w;
            const float* __restrict__ wr = Ws + k * D + c0;
#pragma unroll
            for (int j = 0; j < 8; ++j) acc[j] = fmaf(xv, wr[j], acc[j]);
        }
#pragma unroll
        for (int j = 0; j < 8; ++j) acc[j] += bs[c0 + j] + bn[c0 + j];
        *reinterpret_cast<float4*>(outb + rb + c0) =
            make_float4(acc[0], acc[1], acc[2], acc[3]);
        *reinterpret_cast<float4*>(outb + rb + c0 + 4) =
            make_float4(acc[4], acc[5], acc[6], acc[7]);
    }

    // ---- half 1: hN = x @ Wn ----
#pragma unroll 1
    for (int c0 = 0; c0 < D; c0 += 8) {
        float acc[8];
#pragma unroll
        for (int j = 0; j < 8; ++j) acc[j] = 0.f;
#pragma unroll
        for (int k = 0; k < D; ++k) {
            float4 q = xr[k >> 2];
            float xv = ((k & 3) == 0) ? q.x : ((k & 3) == 1) ? q.y
                     : ((k & 3) == 2) ? q.z : q.w;
            const float* __restrict__ wr = Wn + k * D + c0;
#pragma unroll
            for (int j = 0; j < 8; ++j) acc[j] = fmaf(xv, wr[j], acc[j]);
        }
        *reinterpret_cast<float4*>(hN + rb + c0) =
            make_float4(acc[0], acc[1], acc[2], acc[3]);
        *reinterpret_cast<float4*>(hN + rb + c0 + 4) =
            make_float4(acc[4], acc[5], acc[6], acc[7]);
    }
}

// ---------------- edge scatter: out[dst] += hN[src] * degInv[dst] ----------------
__global__ __launch_bounds__(256) void scatter_kernel(const int* __restrict__ src,
                                                      const int* __restrict__ dst,
                                                      const float* __restrict__ hN,
                                                      const float* __restrict__ degInv,
                                                      float* __restrict__ out, int nE) {
    int tid = blockIdx.x * 256 + threadIdx.x;
    int e = tid >> 7;  // 128 threads (one per channel) per edge
    int c = tid & (D - 1);
    if (e < nE) {
        int s = src[e];
        int d = dst[e];
        float scale = degInv[d];
        float v = hN[(size_t)s * D + c] * scale;
        atomicAdd(&out[(size_t)d * D + c], v);
    }
}

// ---------------- relu ----------------
__global__ __launch_bounds__(256) void relu_kernel(float* __restrict__ out, size_t nElem) {
    size_t n4 = nElem / 4;
    float4* p = reinterpret_cast<float4*>(out);
    for (size_t i = (size_t)blockIdx.x * 256 + threadIdx.x; i < n4;
         i += (size_t)gridDim.x * 256) {
        float4 v = p[i];
        v.x = fmaxf(v.x, 0.f);
        v.y = fmaxf(v.y, 0.f);
        v.z = fmaxf(v.z, 0.f);
        v.w = fmaxf(v.w, 0.f);
        p[i] = v;
    }
}

extern "C" void kernel_launch(void* const* d_in, const int* in_sizes, int n_in,
                              void* d_out, int out_size, void* d_ws, size_t ws_size,
                              hipStream_t stream) {
    const float* x  = (const float*)d_in[0];
    const int*   ei = (const int*)d_in[1];
    const float* Ws = (const float*)d_in[2];
    const float* bs = (const float*)d_in[3];
    const float* Wn = (const float*)d_in[4];
    const float* bn = (const float*)d_in[5];
    float* out = (float*)d_out;

    const int n  = in_sizes[0] / D;   // 100000
    const int nE = in_sizes[1] / 2;   // 640000
    const int* src = ei;
    const int* dst = ei + nE;

    float* hN  = (float*)d_ws;              // n*D f32  (51.2 MB)
    float* deg = hN + (size_t)n * D;        // n   f32  (0.4 MB)

    hipMemsetAsync(deg, 0, (size_t)n * sizeof(float), stream);
    deg_count_kernel<<<(nE + 255) / 256, 256, 0, stream>>>(dst, deg, nE);
    deg_inv_kernel<<<(n + 255) / 256, 256, 0, stream>>>(deg, n);
    gemm_rows_kernel<<<(n + 127) / 128, 128, 0, stream>>>(x, Ws, bs, Wn, bn, out, hN, n);
    scatter_kernel<<<(int)(((size_t)nE * D + 255) / 256), 256, 0, stream>>>(src, dst, hN, deg,
                                                                            out, nE);
    relu_kernel<<<2048, 256, 0, stream>>>(out, (size_t)n * D);
}

// Round 3
// 403.632 us; speedup vs baseline: 10.1054x; 1.6075x over previous
//
#include <hip/hip_runtime.h>

#define D 128

typedef __attribute__((ext_vector_type(8))) short short8v;  // 8 bf16 (4 VGPRs)
typedef __attribute__((ext_vector_type(4))) float f32x4;

__device__ __forceinline__ short f2bf(float f) {
    union { float f; unsigned u; } v;
    v.f = f;
    unsigned u = v.u;
    unsigned r = (u + 0x7FFFu + ((u >> 16) & 1u)) >> 16;  // RNE
    return (short)r;
}

// ---------------- degree count + inverse ----------------
__global__ __launch_bounds__(256) void deg_count_kernel(const int* __restrict__ dst,
                                                        float* __restrict__ deg, int nE) {
    int e = blockIdx.x * 256 + threadIdx.x;
    if (e < nE) atomicAdd(&deg[dst[e]], 1.0f);
}

__global__ __launch_bounds__(256) void deg_inv_kernel(float* __restrict__ deg, int n) {
    int i = blockIdx.x * 256 + threadIdx.x;
    if (i < n) deg[i] = 1.0f / fmaxf(deg[i], 1.0f);
}

// ---------------- pack W = [Ws | Wn] transposed to bf16: WT[n][k], n in [0,256) ----------------
__global__ __launch_bounds__(256) void wt_pack_kernel(const float* __restrict__ Ws,
                                                      const float* __restrict__ Wn,
                                                      short* __restrict__ WT) {
    int idx = blockIdx.x * 256 + threadIdx.x;  // 256*128 = 32768 total
    int nn = idx >> 7;
    int k = idx & (D - 1);
    float v = (nn < D) ? Ws[k * D + nn] : Wn[k * D + (nn - D)];
    WT[idx] = f2bf(v);
}

// ---------------- dual GEMM via bf16 MFMA ----------------
// Wave handles a 16-row strip. A-frag: lane l holds x[m0+(l&15)][(l>>4)*8 + i] (bf16, cvt on fly).
// B-frag: lane l holds WT[ct*16+(l&15)][(l>>4)*8 + i]  (= B^T row-major load).
// C/D: col = lane&15, row = m0 + (lane>>4)*4 + reg   [m89-verified].
__global__ __launch_bounds__(256) void gemm_mfma_kernel(const float* __restrict__ x,
                                                        const short* __restrict__ WT,
                                                        const float* __restrict__ bs,
                                                        const float* __restrict__ bn,
                                                        float* __restrict__ outS,
                                                        float* __restrict__ hN, int n) {
    const int wave = threadIdx.x >> 6;
    const int lane = threadIdx.x & 63;
    const int m0 = (blockIdx.x * 4 + wave) * 16;
    if (m0 >= n) return;  // strips are never partial (n % 16 == 0); no barriers in kernel

    const int lrow = lane & 15;
    const int ko = (lane >> 4) * 8;

    // Load + convert A fragments for the 4 K-steps
    short8v a[4];
    const float* __restrict__ xr = x + (size_t)(m0 + lrow) * D + ko;
#pragma unroll
    for (int s = 0; s < 4; ++s) {
        float4 lo = *reinterpret_cast<const float4*>(xr + s * 32);
        float4 hi = *reinterpret_cast<const float4*>(xr + s * 32 + 4);
        short8v af;
        af[0] = f2bf(lo.x); af[1] = f2bf(lo.y); af[2] = f2bf(lo.z); af[3] = f2bf(lo.w);
        af[4] = f2bf(hi.x); af[5] = f2bf(hi.y); af[6] = f2bf(hi.z); af[7] = f2bf(hi.w);
        a[s] = af;
    }

    f32x4 acc[16];
#pragma unroll
    for (int ct = 0; ct < 16; ++ct) acc[ct] = (f32x4){0.f, 0.f, 0.f, 0.f};

#pragma unroll
    for (int ct = 0; ct < 16; ++ct) {
        const short* __restrict__ wp = WT + (size_t)(ct * 16 + lrow) * D + ko;
#pragma unroll
        for (int s = 0; s < 4; ++s) {
            short8v b = *reinterpret_cast<const short8v*>(wp + s * 32);
            acc[ct] = __builtin_amdgcn_mfma_f32_16x16x32_bf16(a[s], b, acc[ct], 0, 0, 0);
        }
    }

    // Epilogue: col = lane&15, row = m0 + (lane>>4)*4 + reg
    const int r0 = m0 + (lane >> 4) * 4;
#pragma unroll
    for (int ct = 0; ct < 8; ++ct) {
        int c = ct * 16 + lrow;
        float bb = bs[c] + bn[c];
#pragma unroll
        for (int rg = 0; rg < 4; ++rg)
            outS[(size_t)(r0 + rg) * D + c] = acc[ct][rg] + bb;
    }
#pragma unroll
    for (int ct = 8; ct < 16; ++ct) {
        int c = (ct - 8) * 16 + lrow;
#pragma unroll
        for (int rg = 0; rg < 4; ++rg)
            hN[(size_t)(r0 + rg) * D + c] = acc[ct][rg];
    }
}

// ---------------- edge scatter: out[dst] += hN[src] * degInv[dst] ----------------
__global__ __launch_bounds__(256) void scatter_kernel(const int* __restrict__ src,
                                                      const int* __restrict__ dst,
                                                      const float* __restrict__ hN,
                                                      const float* __restrict__ degInv,
                                                      float* __restrict__ out, int nE) {
    int tid = blockIdx.x * 256 + threadIdx.x;
    int e = tid >> 7;  // 128 threads (one per channel) per edge
    int c = tid & (D - 1);
    if (e < nE) {
        int s = src[e];
        int d = dst[e];
        float scale = degInv[d];
        float v = hN[(size_t)s * D + c] * scale;
        atomicAdd(&out[(size_t)d * D + c], v);
    }
}

// ---------------- relu ----------------
__global__ __launch_bounds__(256) void relu_kernel(float* __restrict__ out, size_t nElem) {
    size_t n4 = nElem / 4;
    float4* p = reinterpret_cast<float4*>(out);
    for (size_t i = (size_t)blockIdx.x * 256 + threadIdx.x; i < n4;
         i += (size_t)gridDim.x * 256) {
        float4 v = p[i];
        v.x = fmaxf(v.x, 0.f);
        v.y = fmaxf(v.y, 0.f);
        v.z = fmaxf(v.z, 0.f);
        v.w = fmaxf(v.w, 0.f);
        p[i] = v;
    }
}

extern "C" void kernel_launch(void* const* d_in, const int* in_sizes, int n_in,
                              void* d_out, int out_size, void* d_ws, size_t ws_size,
                              hipStream_t stream) {
    const float* x  = (const float*)d_in[0];
    const int*   ei = (const int*)d_in[1];
    const float* Ws = (const float*)d_in[2];
    const float* bs = (const float*)d_in[3];
    const float* Wn = (const float*)d_in[4];
    const float* bn = (const float*)d_in[5];
    float* out = (float*)d_out;

    const int n  = in_sizes[0] / D;   // 100000
    const int nE = in_sizes[1] / 2;   // 640000
    const int* src = ei;
    const int* dst = ei + nE;

    float* hN  = (float*)d_ws;                 // n*D f32   (51.2 MB)
    float* deg = hN + (size_t)n * D;           // n   f32   (0.4 MB)
    short* WT  = (short*)(deg + n);            // 256*128 bf16 (64 KB)

    wt_pack_kernel<<<(256 * D) / 256, 256, 0, stream>>>(Ws, Wn, WT);
    hipMemsetAsync(deg, 0, (size_t)n * sizeof(float), stream);
    deg_count_kernel<<<(nE + 255) / 256, 256, 0, stream>>>(dst, deg, nE);
    deg_inv_kernel<<<(n + 255) / 256, 256, 0, stream>>>(deg, n);

    const int nStrips = (n + 15) / 16;            // 6250
    gemm_mfma_kernel<<<(nStrips + 3) / 4, 256, 0, stream>>>(x, WT, bs, bn, out, hN, n);

    scatter_kernel<<<(int)(((size_t)nE * D + 255) / 256), 256, 0, stream>>>(src, dst, hN, deg,
                                                                            out, nE);
    relu_kernel<<<2048, 256, 0, stream>>>(out, (size_t)n * D);
}

// Round 4
// 355.808 us; speedup vs baseline: 11.4637x; 1.1344x over previous
//
#include <hip/hip_runtime.h>

#define D 128

typedef __attribute__((ext_vector_type(8))) short short8v;  // 8 bf16 (4 VGPRs)
typedef __attribute__((ext_vector_type(4))) float f32x4;

__device__ __forceinline__ short f2bf(float f) {
    union { float f; unsigned u; } v;
    v.f = f;
    unsigned u = v.u;
    unsigned r = (u + 0x7FFFu + ((u >> 16) & 1u)) >> 16;  // RNE
    return (short)r;
}

__device__ __forceinline__ float bf2f(unsigned u16) {
    union { unsigned u; float f; } v;
    v.u = u16 << 16;
    return v.f;
}

// ---------------- int histogram of dst ----------------
__global__ __launch_bounds__(256) void hist_kernel(const int* __restrict__ dst,
                                                   int* __restrict__ counts, int nE) {
    int e = blockIdx.x * 256 + threadIdx.x;
    if (e < nE) atomicAdd(&counts[dst[e]], 1);
}

// ---------------- single-WG exclusive scan: counts -> rowptr ----------------
__global__ __launch_bounds__(1024) void scan_kernel(const int* __restrict__ counts,
                                                    int* __restrict__ rowptr, int n) {
    __shared__ int sums[1024];
    const int t = threadIdx.x;
    const int chunk = (n + 1023) / 1024;
    const int lo = t * chunk;
    const int hi = min(lo + chunk, n);
    int s = 0;
    for (int i = lo; i < hi; ++i) s += counts[i];
    sums[t] = s;
    __syncthreads();
    // Hillis-Steele inclusive scan
    for (int off = 1; off < 1024; off <<= 1) {
        int v = (t >= off) ? sums[t - off] : 0;
        __syncthreads();
        sums[t] += v;
        __syncthreads();
    }
    int run = (t == 0) ? 0 : sums[t - 1];
    if (t == 0) rowptr[n] = sums[1023];
    for (int i = lo; i < hi; ++i) {
        rowptr[i] = run;
        run += counts[i];
    }
}

// ---------------- degInv from counts; counts <- rowptr (becomes cursor) ----------------
__global__ __launch_bounds__(256) void deginv_cursor_kernel(int* __restrict__ counts,
                                                            const int* __restrict__ rowptr,
                                                            float* __restrict__ degInv, int n) {
    int i = blockIdx.x * 256 + threadIdx.x;
    if (i < n) {
        degInv[i] = 1.0f / fmaxf((float)counts[i], 1.0f);
        counts[i] = rowptr[i];  // cursor init
    }
}

// ---------------- CSR fill: csr[pos] = src, pos = cursor[dst]++ ----------------
__global__ __launch_bounds__(256) void fill_kernel(const int* __restrict__ src,
                                                   const int* __restrict__ dst,
                                                   int* __restrict__ cursor,
                                                   int* __restrict__ csr, int nE) {
    int e = blockIdx.x * 256 + threadIdx.x;
    if (e < nE) {
        int pos = atomicAdd(&cursor[dst[e]], 1);
        csr[pos] = src[e];
    }
}

// ---------------- pack W = [Ws | Wn] transposed to bf16: WT[n][k], n in [0,256) ----------------
__global__ __launch_bounds__(256) void wt_pack_kernel(const float* __restrict__ Ws,
                                                      const float* __restrict__ Wn,
                                                      short* __restrict__ WT) {
    int idx = blockIdx.x * 256 + threadIdx.x;  // 256*128 = 32768 total
    int nn = idx >> 7;
    int k = idx & (D - 1);
    float v = (nn < D) ? Ws[k * D + nn] : Wn[k * D + (nn - D)];
    WT[idx] = f2bf(v);
}

// ---------------- dual GEMM via bf16 MFMA ----------------
// Wave: 16-row strip. A: lane l holds x[m0+(l&15)][(l>>4)*8+i] (cvt f32->bf16 on fly).
// B: lane l holds WT[ct*16+(l&15)][(l>>4)*8+i] (B^T row-major). C/D: col=lane&15,
// row=(lane>>4)*4+reg [m89]. outS gets x@Ws+bs+bn (f32); hN gets x@Wn as bf16.
__global__ __launch_bounds__(256) void gemm_mfma_kernel(const float* __restrict__ x,
                                                        const short* __restrict__ WT,
                                                        const float* __restrict__ bs,
                                                        const float* __restrict__ bn,
                                                        float* __restrict__ outS,
                                                        unsigned short* __restrict__ hNb,
                                                        int n) {
    const int wave = threadIdx.x >> 6;
    const int lane = threadIdx.x & 63;
    const int m0 = (blockIdx.x * 4 + wave) * 16;
    if (m0 >= n) return;  // n % 16 == 0; no barriers in this kernel

    const int lrow = lane & 15;
    const int ko = (lane >> 4) * 8;

    short8v a[4];
    const float* __restrict__ xr = x + (size_t)(m0 + lrow) * D + ko;
#pragma unroll
    for (int s = 0; s < 4; ++s) {
        float4 lo = *reinterpret_cast<const float4*>(xr + s * 32);
        float4 hi = *reinterpret_cast<const float4*>(xr + s * 32 + 4);
        short8v af;
        af[0] = f2bf(lo.x); af[1] = f2bf(lo.y); af[2] = f2bf(lo.z); af[3] = f2bf(lo.w);
        af[4] = f2bf(hi.x); af[5] = f2bf(hi.y); af[6] = f2bf(hi.z); af[7] = f2bf(hi.w);
        a[s] = af;
    }

    f32x4 acc[16];
#pragma unroll
    for (int ct = 0; ct < 16; ++ct) acc[ct] = (f32x4){0.f, 0.f, 0.f, 0.f};

#pragma unroll
    for (int ct = 0; ct < 16; ++ct) {
        const short* __restrict__ wp = WT + (size_t)(ct * 16 + lrow) * D + ko;
#pragma unroll
        for (int s = 0; s < 4; ++s) {
            short8v b = *reinterpret_cast<const short8v*>(wp + s * 32);
            acc[ct] = __builtin_amdgcn_mfma_f32_16x16x32_bf16(a[s], b, acc[ct], 0, 0, 0);
        }
    }

    const int r0 = m0 + (lane >> 4) * 4;
#pragma unroll
    for (int ct = 0; ct < 8; ++ct) {
        int c = ct * 16 + lrow;
        float bb = bs[c] + bn[c];
#pragma unroll
        for (int rg = 0; rg < 4; ++rg)
            outS[(size_t)(r0 + rg) * D + c] = acc[ct][rg] + bb;
    }
#pragma unroll
    for (int ct = 8; ct < 16; ++ct) {
        int c = (ct - 8) * 16 + lrow;
#pragma unroll
        for (int rg = 0; rg < 4; ++rg)
            hNb[(size_t)(r0 + rg) * D + c] = (unsigned short)f2bf(acc[ct][rg]);
    }
}

// ---------------- gather: out[d] = relu(outS[d] + degInv[d] * sum_{e in csr[d]} hN[src_e]) ----
// One wave per node; lane handles channels {2*lane, 2*lane+1} (one dword of bf16x2 per gather).
__global__ __launch_bounds__(256) void gather_kernel(const int* __restrict__ rowptr,
                                                     const int* __restrict__ csr,
                                                     const unsigned short* __restrict__ hNb,
                                                     const float* __restrict__ degInv,
                                                     float* __restrict__ out, int n) {
    const int wave = threadIdx.x >> 6;
    const int lane = threadIdx.x & 63;
    const int d = blockIdx.x * 4 + wave;
    if (d >= n) return;  // no barriers

    const int beg = rowptr[d];
    const int end = rowptr[d + 1];
    float ax = 0.f, ay = 0.f;

    int i = beg;
    for (; i + 1 < end; i += 2) {
        int s0 = csr[i];
        int s1 = csr[i + 1];
        unsigned v0 = *reinterpret_cast<const unsigned*>(hNb + (size_t)s0 * D + lane * 2);
        unsigned v1 = *reinterpret_cast<const unsigned*>(hNb + (size_t)s1 * D + lane * 2);
        ax += bf2f(v0 & 0xffffu) + bf2f(v1 & 0xffffu);
        ay += bf2f(v0 >> 16) + bf2f(v1 >> 16);
    }
    if (i < end) {
        int s0 = csr[i];
        unsigned v0 = *reinterpret_cast<const unsigned*>(hNb + (size_t)s0 * D + lane * 2);
        ax += bf2f(v0 & 0xffffu);
        ay += bf2f(v0 >> 16);
    }

    const float inv = degInv[d];
    float2 o = *reinterpret_cast<const float2*>(out + (size_t)d * D + lane * 2);
    o.x = fmaxf(fmaf(ax, inv, o.x), 0.f);
    o.y = fmaxf(fmaf(ay, inv, o.y), 0.f);
    *reinterpret_cast<float2*>(out + (size_t)d * D + lane * 2) = o;
}

extern "C" void kernel_launch(void* const* d_in, const int* in_sizes, int n_in,
                              void* d_out, int out_size, void* d_ws, size_t ws_size,
                              hipStream_t stream) {
    const float* x  = (const float*)d_in[0];
    const int*   ei = (const int*)d_in[1];
    const float* Ws = (const float*)d_in[2];
    const float* bs = (const float*)d_in[3];
    const float* Wn = (const float*)d_in[4];
    const float* bn = (const float*)d_in[5];
    float* out = (float*)d_out;

    const int n  = in_sizes[0] / D;   // 100000
    const int nE = in_sizes[1] / 2;   // 640000
    const int* src = ei;
    const int* dst = ei + nE;

    // workspace layout (~29.4 MB)
    unsigned short* hNb = (unsigned short*)d_ws;          // n*D bf16 (25.6 MB)
    short* WT    = (short*)(hNb + (size_t)n * D);         // 256*128 bf16 (64 KB)
    int*   counts = (int*)(WT + 256 * D);                 // n int (cursor after scan)
    int*   rowptr = counts + n;                           // n+1 int
    float* degInv = (float*)(rowptr + n + 1);             // n f32
    int*   csr    = (int*)(degInv + n);                   // nE int (2.56 MB)

    hipMemsetAsync(counts, 0, (size_t)n * sizeof(int), stream);
    hist_kernel<<<(nE + 255) / 256, 256, 0, stream>>>(dst, counts, nE);
    scan_kernel<<<1, 1024, 0, stream>>>(counts, rowptr, n);
    deginv_cursor_kernel<<<(n + 255) / 256, 256, 0, stream>>>(counts, rowptr, degInv, n);
    fill_kernel<<<(nE + 255) / 256, 256, 0, stream>>>(src, dst, counts, csr, nE);

    wt_pack_kernel<<<(256 * D) / 256, 256, 0, stream>>>(Ws, Wn, WT);
    const int nStrips = (n + 15) / 16;  // 6250
    gemm_mfma_kernel<<<(nStrips + 3) / 4, 256, 0, stream>>>(x, WT, bs, bn, out, hNb, n);

    gather_kernel<<<(n + 3) / 4, 256, 0, stream>>>(rowptr, csr, hNb, degInv, out, n);
}

// Round 5
// 201.225 us; speedup vs baseline: 20.2703x; 1.7682x over previous
//
#include <hip/hip_runtime.h>

#define D 128

typedef __attribute__((ext_vector_type(8))) short short8v;  // 8 bf16 (4 VGPRs)
typedef __attribute__((ext_vector_type(4))) float f32x4;

__device__ __forceinline__ short f2bf(float f) {
    union { float f; unsigned u; } v;
    v.f = f;
    unsigned u = v.u;
    unsigned r = (u + 0x7FFFu + ((u >> 16) & 1u)) >> 16;  // RNE
    return (short)r;
}

__device__ __forceinline__ float bf2f(unsigned u16) {
    union { unsigned u; float f; } v;
    v.u = u16 << 16;
    return v.f;
}

// ---------------- int histogram of dst ----------------
__global__ __launch_bounds__(256) void hist_kernel(const int* __restrict__ dst,
                                                   int* __restrict__ counts, int nE) {
    int e = blockIdx.x * 256 + threadIdx.x;
    if (e < nE) atomicAdd(&counts[dst[e]], 1);
}

// ---------------- scan A: per-block (1024-chunk) totals ----------------
__global__ __launch_bounds__(256) void scan_partial_kernel(const int* __restrict__ counts,
                                                           int* __restrict__ bsums, int n) {
    __shared__ int wsum[4];
    const int t = threadIdx.x;
    const int i0 = blockIdx.x * 1024 + t * 4;
    int s = 0;
#pragma unroll
    for (int j = 0; j < 4; ++j) s += (i0 + j < n) ? counts[i0 + j] : 0;
#pragma unroll
    for (int off = 32; off > 0; off >>= 1) s += __shfl_down(s, off, 64);
    if ((t & 63) == 0) wsum[t >> 6] = s;
    __syncthreads();
    if (t == 0) bsums[blockIdx.x] = wsum[0] + wsum[1] + wsum[2] + wsum[3];
}

// ---------------- scan B: exclusive scan of block sums (nb <= 128) ----------------
__global__ __launch_bounds__(128) void scan_bsums_kernel(const int* __restrict__ bsums,
                                                         int* __restrict__ ebsums,
                                                         int* __restrict__ rowptr_n,
                                                         int nb) {
    __shared__ int sh[128];
    const int t = threadIdx.x;
    int v = (t < nb) ? bsums[t] : 0;
    sh[t] = v;
    __syncthreads();
    for (int off = 1; off < 128; off <<= 1) {
        int u = (t >= off) ? sh[t - off] : 0;
        __syncthreads();
        sh[t] += u;
        __syncthreads();
    }
    if (t < nb) ebsums[t] = sh[t] - v;  // exclusive
    if (t == 127) *rowptr_n = sh[127];  // grand total -> rowptr[n]
}

// ---------------- scan C: chunk exclusive scan + degInv + cursor init ----------------
// counts is read then overwritten (cursor) by the SAME thread -> no race.
__global__ __launch_bounds__(256) void scan_final_kernel(int* __restrict__ counts,
                                                         const int* __restrict__ ebsums,
                                                         int* __restrict__ rowptr,
                                                         float* __restrict__ degInv, int n) {
    __shared__ int sh[256];
    const int t = threadIdx.x;
    const int i0 = blockIdx.x * 1024 + t * 4;
    int c[4];
    int s = 0;
#pragma unroll
    for (int j = 0; j < 4; ++j) {
        c[j] = (i0 + j < n) ? counts[i0 + j] : 0;
        s += c[j];
    }
    sh[t] = s;
    __syncthreads();
    for (int off = 1; off < 256; off <<= 1) {
        int u = (t >= off) ? sh[t - off] : 0;
        __syncthreads();
        sh[t] += u;
        __syncthreads();
    }
    int run = ebsums[blockIdx.x] + sh[t] - s;  // exclusive prefix for this thread's 4 elems
#pragma unroll
    for (int j = 0; j < 4; ++j) {
        int i = i0 + j;
        if (i < n) {
            rowptr[i] = run;
            degInv[i] = 1.0f / fmaxf((float)c[j], 1.0f);
            counts[i] = run;  // cursor init
            run += c[j];
        }
    }
}

// ---------------- CSR fill: csr[pos] = src, pos = cursor[dst]++ ----------------
__global__ __launch_bounds__(256) void fill_kernel(const int* __restrict__ src,
                                                   const int* __restrict__ dst,
                                                   int* __restrict__ cursor,
                                                   int* __restrict__ csr, int nE) {
    int e = blockIdx.x * 256 + threadIdx.x;
    if (e < nE) {
        int pos = atomicAdd(&cursor[dst[e]], 1);
        csr[pos] = src[e];
    }
}

// ---------------- pack W = [Ws | Wn] transposed to bf16: WT[n][k], n in [0,256) ----------------
__global__ __launch_bounds__(256) void wt_pack_kernel(const float* __restrict__ Ws,
                                                      const float* __restrict__ Wn,
                                                      short* __restrict__ WT) {
    int idx = blockIdx.x * 256 + threadIdx.x;  // 256*128 = 32768 total
    int nn = idx >> 7;
    int k = idx & (D - 1);
    float v = (nn < D) ? Ws[k * D + nn] : Wn[k * D + (nn - D)];
    WT[idx] = f2bf(v);
}

// ---------------- dual GEMM via bf16 MFMA ----------------
// Wave: 16-row strip. A: lane l holds x[m0+(l&15)][(l>>4)*8+i] (cvt f32->bf16 on fly).
// B: lane l holds WT[ct*16+(l&15)][(l>>4)*8+i] (B^T row-major). C/D: col=lane&15,
// row=(lane>>4)*4+reg [m89]. outS gets x@Ws+bs+bn (f32); hN gets x@Wn as bf16.
__global__ __launch_bounds__(256) void gemm_mfma_kernel(const float* __restrict__ x,
                                                        const short* __restrict__ WT,
                                                        const float* __restrict__ bs,
                                                        const float* __restrict__ bn,
                                                        float* __restrict__ outS,
                                                        unsigned short* __restrict__ hNb,
                                                        int n) {
    const int wave = threadIdx.x >> 6;
    const int lane = threadIdx.x & 63;
    const int m0 = (blockIdx.x * 4 + wave) * 16;
    if (m0 >= n) return;  // n % 16 == 0; no barriers in this kernel

    const int lrow = lane & 15;
    const int ko = (lane >> 4) * 8;

    short8v a[4];
    const float* __restrict__ xr = x + (size_t)(m0 + lrow) * D + ko;
#pragma unroll
    for (int s = 0; s < 4; ++s) {
        float4 lo = *reinterpret_cast<const float4*>(xr + s * 32);
        float4 hi = *reinterpret_cast<const float4*>(xr + s * 32 + 4);
        short8v af;
        af[0] = f2bf(lo.x); af[1] = f2bf(lo.y); af[2] = f2bf(lo.z); af[3] = f2bf(lo.w);
        af[4] = f2bf(hi.x); af[5] = f2bf(hi.y); af[6] = f2bf(hi.z); af[7] = f2bf(hi.w);
        a[s] = af;
    }

    f32x4 acc[16];
#pragma unroll
    for (int ct = 0; ct < 16; ++ct) acc[ct] = (f32x4){0.f, 0.f, 0.f, 0.f};

#pragma unroll
    for (int ct = 0; ct < 16; ++ct) {
        const short* __restrict__ wp = WT + (size_t)(ct * 16 + lrow) * D + ko;
#pragma unroll
        for (int s = 0; s < 4; ++s) {
            short8v b = *reinterpret_cast<const short8v*>(wp + s * 32);
            acc[ct] = __builtin_amdgcn_mfma_f32_16x16x32_bf16(a[s], b, acc[ct], 0, 0, 0);
        }
    }

    const int r0 = m0 + (lane >> 4) * 4;
#pragma unroll
    for (int ct = 0; ct < 8; ++ct) {
        int c = ct * 16 + lrow;
        float bb = bs[c] + bn[c];
#pragma unroll
        for (int rg = 0; rg < 4; ++rg)
            outS[(size_t)(r0 + rg) * D + c] = acc[ct][rg] + bb;
    }
#pragma unroll
    for (int ct = 8; ct < 16; ++ct) {
        int c = (ct - 8) * 16 + lrow;
#pragma unroll
        for (int rg = 0; rg < 4; ++rg)
            hNb[(size_t)(r0 + rg) * D + c] = (unsigned short)f2bf(acc[ct][rg]);
    }
}

// ---------------- gather: out[d] = relu(outS[d] + degInv[d] * sum_{e in csr[d]} hN[src_e]) ----
// One wave per node; lane handles channels {2*lane, 2*lane+1} (one dword of bf16x2 per gather).
__global__ __launch_bounds__(256) void gather_kernel(const int* __restrict__ rowptr,
                                                     const int* __restrict__ csr,
                                                     const unsigned short* __restrict__ hNb,
                                                     const float* __restrict__ degInv,
                                                     float* __restrict__ out, int n) {
    const int wave = threadIdx.x >> 6;
    const int lane = threadIdx.x & 63;
    const int d = blockIdx.x * 4 + wave;
    if (d >= n) return;  // no barriers

    const int beg = rowptr[d];
    const int end = rowptr[d + 1];
    float ax = 0.f, ay = 0.f;

    int i = beg;
    for (; i + 1 < end; i += 2) {
        int s0 = csr[i];
        int s1 = csr[i + 1];
        unsigned v0 = *reinterpret_cast<const unsigned*>(hNb + (size_t)s0 * D + lane * 2);
        unsigned v1 = *reinterpret_cast<const unsigned*>(hNb + (size_t)s1 * D + lane * 2);
        ax += bf2f(v0 & 0xffffu) + bf2f(v1 & 0xffffu);
        ay += bf2f(v0 >> 16) + bf2f(v1 >> 16);
    }
    if (i < end) {
        int s0 = csr[i];
        unsigned v0 = *reinterpret_cast<const unsigned*>(hNb + (size_t)s0 * D + lane * 2);
        ax += bf2f(v0 & 0xffffu);
        ay += bf2f(v0 >> 16);
    }

    const float inv = degInv[d];
    float2 o = *reinterpret_cast<const float2*>(out + (size_t)d * D + lane * 2);
    o.x = fmaxf(fmaf(ax, inv, o.x), 0.f);
    o.y = fmaxf(fmaf(ay, inv, o.y), 0.f);
    *reinterpret_cast<float2*>(out + (size_t)d * D + lane * 2) = o;
}

extern "C" void kernel_launch(void* const* d_in, const int* in_sizes, int n_in,
                              void* d_out, int out_size, void* d_ws, size_t ws_size,
                              hipStream_t stream) {
    const float* x  = (const float*)d_in[0];
    const int*   ei = (const int*)d_in[1];
    const float* Ws = (const float*)d_in[2];
    const float* bs = (const float*)d_in[3];
    const float* Wn = (const float*)d_in[4];
    const float* bn = (const float*)d_in[5];
    float* out = (float*)d_out;

    const int n  = in_sizes[0] / D;   // 100000
    const int nE = in_sizes[1] / 2;   // 640000
    const int* src = ei;
    const int* dst = ei + nE;
    const int nb = (n + 1023) / 1024; // 98 (<=128 by problem size)

    // workspace layout (~29.4 MB)
    unsigned short* hNb = (unsigned short*)d_ws;          // n*D bf16 (25.6 MB)
    short* WT    = (short*)(hNb + (size_t)n * D);         // 256*128 bf16 (64 KB)
    int*   counts = (int*)(WT + 256 * D);                 // n int (becomes cursor)
    int*   rowptr = counts + n;                           // n+1 int
    float* degInv = (float*)(rowptr + n + 1);             // n f32
    int*   csr    = (int*)(degInv + n);                   // nE int (2.56 MB)
    int*   bsums  = csr + nE;                             // 128 int
    int*   ebsums = bsums + 128;                          // 128 int

    hipMemsetAsync(counts, 0, (size_t)n * sizeof(int), stream);
    hist_kernel<<<(nE + 255) / 256, 256, 0, stream>>>(dst, counts, nE);
    scan_partial_kernel<<<nb, 256, 0, stream>>>(counts, bsums, n);
    scan_bsums_kernel<<<1, 128, 0, stream>>>(bsums, ebsums, rowptr + n, nb);
    scan_final_kernel<<<nb, 256, 0, stream>>>(counts, ebsums, rowptr, degInv, n);
    fill_kernel<<<(nE + 255) / 256, 256, 0, stream>>>(src, dst, counts, csr, nE);

    wt_pack_kernel<<<(256 * D) / 256, 256, 0, stream>>>(Ws, Wn, WT);
    const int nStrips = (n + 15) / 16;  // 6250
    gemm_mfma_kernel<<<(nStrips + 3) / 4, 256, 0, stream>>>(x, WT, bs, bn, out, hNb, n);

    gather_kernel<<<(n + 3) / 4, 256, 0, stream>>>(rowptr, csr, hNb, degInv, out, n);
}

// Round 6
// 169.853 us; speedup vs baseline: 24.0142x; 1.1847x over previous
//
#include <hip/hip_runtime.h>
#include <hip/hip_bf16.h>

#define D 128

typedef __attribute__((ext_vector_type(8))) short short8v;  // 8 bf16 (4 VGPRs)
typedef __attribute__((ext_vector_type(4))) float f32x4;

__device__ __forceinline__ short f2bf(float f) {
    union { float f; unsigned u; } v;
    v.f = f;
    unsigned u = v.u;
    unsigned r = (u + 0x7FFFu + ((u >> 16) & 1u)) >> 16;  // RNE
    return (short)r;
}

__device__ __forceinline__ float bf2f(unsigned u16) {
    union { unsigned u; float f; } v;
    v.u = u16 << 16;
    return v.f;
}

// pack two f32 -> one dword of 2 bf16 (compiler emits v_cvt_pk_bf16_f32)
__device__ __forceinline__ unsigned pkbf2(float lo, float hi) {
    __hip_bfloat162 h = __float22bfloat162_rn(make_float2(lo, hi));
    union { __hip_bfloat162 h; unsigned u; } v;
    v.h = h;
    return v.u;
}

// ---------------- int histogram of dst ----------------
__global__ __launch_bounds__(256) void hist_kernel(const int* __restrict__ dst,
                                                   int* __restrict__ counts, int nE) {
    int e = blockIdx.x * 256 + threadIdx.x;
    if (e < nE) atomicAdd(&counts[dst[e]], 1);
}

// ---------------- scan A: per-block (1024-chunk) totals ----------------
__global__ __launch_bounds__(256) void scan_partial_kernel(const int* __restrict__ counts,
                                                           int* __restrict__ bsums, int n) {
    __shared__ int wsum[4];
    const int t = threadIdx.x;
    const int i0 = blockIdx.x * 1024 + t * 4;
    int s = 0;
#pragma unroll
    for (int j = 0; j < 4; ++j) s += (i0 + j < n) ? counts[i0 + j] : 0;
#pragma unroll
    for (int off = 32; off > 0; off >>= 1) s += __shfl_down(s, off, 64);
    if ((t & 63) == 0) wsum[t >> 6] = s;
    __syncthreads();
    if (t == 0) bsums[blockIdx.x] = wsum[0] + wsum[1] + wsum[2] + wsum[3];
}

// ---------------- scan B: exclusive scan of block sums (nb <= 128) ----------------
__global__ __launch_bounds__(128) void scan_bsums_kernel(const int* __restrict__ bsums,
                                                         int* __restrict__ ebsums,
                                                         int* __restrict__ rowptr_n,
                                                         int nb) {
    __shared__ int sh[128];
    const int t = threadIdx.x;
    int v = (t < nb) ? bsums[t] : 0;
    sh[t] = v;
    __syncthreads();
    for (int off = 1; off < 128; off <<= 1) {
        int u = (t >= off) ? sh[t - off] : 0;
        __syncthreads();
        sh[t] += u;
        __syncthreads();
    }
    if (t < nb) ebsums[t] = sh[t] - v;  // exclusive
    if (t == 127) *rowptr_n = sh[127];  // grand total -> rowptr[n]
}

// ---------------- scan C: chunk exclusive scan + cursor init ----------------
__global__ __launch_bounds__(256) void scan_final_kernel(int* __restrict__ counts,
                                                         const int* __restrict__ ebsums,
                                                         int* __restrict__ rowptr, int n) {
    __shared__ int sh[256];
    const int t = threadIdx.x;
    const int i0 = blockIdx.x * 1024 + t * 4;
    int c[4];
    int s = 0;
#pragma unroll
    for (int j = 0; j < 4; ++j) {
        c[j] = (i0 + j < n) ? counts[i0 + j] : 0;
        s += c[j];
    }
    sh[t] = s;
    __syncthreads();
    for (int off = 1; off < 256; off <<= 1) {
        int u = (t >= off) ? sh[t - off] : 0;
        __syncthreads();
        sh[t] += u;
        __syncthreads();
    }
    int run = ebsums[blockIdx.x] + sh[t] - s;
#pragma unroll
    for (int j = 0; j < 4; ++j) {
        int i = i0 + j;
        if (i < n) {
            rowptr[i] = run;
            counts[i] = run;  // cursor init
            run += c[j];
        }
    }
}

// ---------------- CSR fill: csr[pos] = src, pos = cursor[dst]++ ----------------
__global__ __launch_bounds__(256) void fill_kernel(const int* __restrict__ src,
                                                   const int* __restrict__ dst,
                                                   int* __restrict__ cursor,
                                                   int* __restrict__ csr, int nE) {
    int e = blockIdx.x * 256 + threadIdx.x;
    if (e < nE) {
        int pos = atomicAdd(&cursor[dst[e]], 1);
        csr[pos] = src[e];
    }
}

// ---------------- pack W = [Ws | Wn] transposed to bf16: WT[n][k], n in [0,256) ----------------
__global__ __launch_bounds__(256) void wt_pack_kernel(const float* __restrict__ Ws,
                                                      const float* __restrict__ Wn,
                                                      short* __restrict__ WT) {
    int idx = blockIdx.x * 256 + threadIdx.x;  // 256*128 = 32768 total
    int nn = idx >> 7;
    int k = idx & (D - 1);
    float v = (nn < D) ? Ws[k * D + nn] : Wn[k * D + (nn - D)];
    WT[idx] = f2bf(v);
}

// ---------------- persistent dual GEMM via bf16 MFMA ----------------
// 4 waves/block; wave owns 4 of 16 column-tiles; B-frags live in regs for the whole
// kernel (loaded once). Blocks grid-stride over 16-row strips with double-buffered
// A prefetch. Waves 0-1 write outS=x@Ws+bs+bn (f32, to d_out); waves 2-3 write
// hNb=x@Wn (bf16). C/D: col=lane&15, row=(lane>>4)*4+reg [m89].
__global__ __launch_bounds__(256) void gemm_mfma_kernel(const float* __restrict__ x,
                                                        const short* __restrict__ WT,
                                                        const float* __restrict__ bs,
                                                        const float* __restrict__ bn,
                                                        float* __restrict__ outS,
                                                        unsigned short* __restrict__ hNb,
                                                        int nStrips) {
    const int wave = threadIdx.x >> 6;
    const int lane = threadIdx.x & 63;
    const int lrow = lane & 15;
    const int ko = (lane >> 4) * 8;
    const bool isS = (wave < 2);

    // B fragments: 4 col-tiles x 4 K-steps, resident in registers
    short8v b[4][4];
#pragma unroll
    for (int j = 0; j < 4; ++j) {
        const int ct = wave * 4 + j;
        const short* __restrict__ wp = WT + (size_t)(ct * 16 + lrow) * D + ko;
#pragma unroll
        for (int ks = 0; ks < 4; ++ks)
            b[j][ks] = *reinterpret_cast<const short8v*>(wp + ks * 32);
    }

    float bias[4];
#pragma unroll
    for (int j = 0; j < 4; ++j) {
        int c = ((wave & 1) * 4 + j) * 16 + lrow;
        bias[j] = isS ? (bs[c] + bn[c]) : 0.f;
    }

    const int stride = gridDim.x;

    auto loadA = [&](int strip, float4* fa) {
        const float* __restrict__ xr = x + ((size_t)strip * 16 + lrow) * D + ko;
#pragma unroll
        for (int s = 0; s < 4; ++s) {
            fa[2 * s] = *reinterpret_cast<const float4*>(xr + s * 32);
            fa[2 * s + 1] = *reinterpret_cast<const float4*>(xr + s * 32 + 4);
        }
    };

    auto compute = [&](int strip, const float4* cur) {
        short8v a[4];
#pragma unroll
        for (int s = 0; s < 4; ++s) {
            const float4 lo = cur[2 * s], hi = cur[2 * s + 1];
            union { short8v s8; unsigned u[4]; } af;
            af.u[0] = pkbf2(lo.x, lo.y);
            af.u[1] = pkbf2(lo.z, lo.w);
            af.u[2] = pkbf2(hi.x, hi.y);
            af.u[3] = pkbf2(hi.z, hi.w);
            a[s] = af.s8;
        }
        f32x4 acc[4];
#pragma unroll
        for (int j = 0; j < 4; ++j) acc[j] = (f32x4){0.f, 0.f, 0.f, 0.f};
#pragma unroll
        for (int j = 0; j < 4; ++j)
#pragma unroll
            for (int ks = 0; ks < 4; ++ks)
                acc[j] = __builtin_amdgcn_mfma_f32_16x16x32_bf16(a[ks], b[j][ks], acc[j], 0, 0, 0);

        const int r0 = strip * 16 + (lane >> 4) * 4;
        if (isS) {
#pragma unroll
            for (int j = 0; j < 4; ++j) {
                int c = ((wave & 1) * 4 + j) * 16 + lrow;
#pragma unroll
                for (int rg = 0; rg < 4; ++rg)
                    outS[(size_t)(r0 + rg) * D + c] = acc[j][rg] + bias[j];
            }
        } else {
#pragma unroll
            for (int j = 0; j < 4; ++j) {
                int c = ((wave & 1) * 4 + j) * 16 + lrow;
#pragma unroll
                for (int rg = 0; rg < 4; ++rg)
                    hNb[(size_t)(r0 + rg) * D + c] = (unsigned short)f2bf(acc[j][rg]);
            }
        }
    };

    float4 faA[8], faB[8];
    int strip = blockIdx.x;
    if (strip >= nStrips) return;
    loadA(strip, faA);
    for (; strip < nStrips; strip += 2 * stride) {
        const int s1 = strip + stride;
        if (s1 < nStrips) loadA(s1, faB);
        compute(strip, faA);
        if (s1 < nStrips) {
            const int s2 = s1 + stride;
            if (s2 < nStrips) loadA(s2, faA);
            compute(s1, faB);
        }
    }
}

// ---------------- gather: out[d] = relu(outS[d] + (1/deg)*sum_{e in csr[d]} hN[src_e]) ----
// One wave per node; lane handles channels {2*lane, 2*lane+1}; edge loop unrolled x4.
__global__ __launch_bounds__(256) void gather_kernel(const int* __restrict__ rowptr,
                                                     const int* __restrict__ csr,
                                                     const unsigned short* __restrict__ hNb,
                                                     float* __restrict__ out, int n) {
    const int wave = threadIdx.x >> 6;
    const int lane = threadIdx.x & 63;
    const int d = blockIdx.x * 4 + wave;
    if (d >= n) return;  // no barriers

    const int beg = rowptr[d];
    const int end = rowptr[d + 1];
    float ax = 0.f, ay = 0.f;

    int i = beg;
    for (; i + 3 < end; i += 4) {
        int s0 = csr[i], s1 = csr[i + 1], s2 = csr[i + 2], s3 = csr[i + 3];
        unsigned v0 = *reinterpret_cast<const unsigned*>(hNb + (size_t)s0 * D + lane * 2);
        unsigned v1 = *reinterpret_cast<const unsigned*>(hNb + (size_t)s1 * D + lane * 2);
        unsigned v2 = *reinterpret_cast<const unsigned*>(hNb + (size_t)s2 * D + lane * 2);
        unsigned v3 = *reinterpret_cast<const unsigned*>(hNb + (size_t)s3 * D + lane * 2);
        ax += (bf2f(v0 & 0xffffu) + bf2f(v1 & 0xffffu)) +
              (bf2f(v2 & 0xffffu) + bf2f(v3 & 0xffffu));
        ay += (bf2f(v0 >> 16) + bf2f(v1 >> 16)) + (bf2f(v2 >> 16) + bf2f(v3 >> 16));
    }
    for (; i < end; ++i) {
        int s0 = csr[i];
        unsigned v0 = *reinterpret_cast<const unsigned*>(hNb + (size_t)s0 * D + lane * 2);
        ax += bf2f(v0 & 0xffffu);
        ay += bf2f(v0 >> 16);
    }

    const float inv = 1.0f / fmaxf((float)(end - beg), 1.0f);
    float2 o = *reinterpret_cast<const float2*>(out + (size_t)d * D + lane * 2);
    o.x = fmaxf(fmaf(ax, inv, o.x), 0.f);
    o.y = fmaxf(fmaf(ay, inv, o.y), 0.f);
    *reinterpret_cast<float2*>(out + (size_t)d * D + lane * 2) = o;
}

extern "C" void kernel_launch(void* const* d_in, const int* in_sizes, int n_in,
                              void* d_out, int out_size, void* d_ws, size_t ws_size,
                              hipStream_t stream) {
    const float* x  = (const float*)d_in[0];
    const int*   ei = (const int*)d_in[1];
    const float* Ws = (const float*)d_in[2];
    const float* bs = (const float*)d_in[3];
    const float* Wn = (const float*)d_in[4];
    const float* bn = (const float*)d_in[5];
    float* out = (float*)d_out;

    const int n  = in_sizes[0] / D;   // 100000
    const int nE = in_sizes[1] / 2;   // 640000
    const int* src = ei;
    const int* dst = ei + nE;
    const int nb = (n + 1023) / 1024; // 98

    // workspace layout (~29 MB)
    unsigned short* hNb = (unsigned short*)d_ws;          // n*D bf16 (25.6 MB)
    short* WT    = (short*)(hNb + (size_t)n * D);         // 256*128 bf16 (64 KB)
    int*   counts = (int*)(WT + 256 * D);                 // n int (becomes cursor)
    int*   rowptr = counts + n;                           // n+1 int
    int*   csr    = rowptr + n + 1;                       // nE int (2.56 MB)
    int*   bsums  = csr + nE;                             // 128 int
    int*   ebsums = bsums + 128;                          // 128 int

    hipMemsetAsync(counts, 0, (size_t)n * sizeof(int), stream);
    hist_kernel<<<(nE + 255) / 256, 256, 0, stream>>>(dst, counts, nE);
    scan_partial_kernel<<<nb, 256, 0, stream>>>(counts, bsums, n);
    scan_bsums_kernel<<<1, 128, 0, stream>>>(bsums, ebsums, rowptr + n, nb);
    scan_final_kernel<<<nb, 256, 0, stream>>>(counts, ebsums, rowptr, n);
    fill_kernel<<<(nE + 255) / 256, 256, 0, stream>>>(src, dst, counts, csr, nE);

    wt_pack_kernel<<<(256 * D) / 256, 256, 0, stream>>>(Ws, Wn, WT);
    const int nStrips = (n + 15) / 16;  // 6250
    const int gGrid = nStrips < 1024 ? nStrips : 1024;
    gemm_mfma_kernel<<<gGrid, 256, 0, stream>>>(x, WT, bs, bn, out, hNb, nStrips);

    gather_kernel<<<(n + 3) / 4, 256, 0, stream>>>(rowptr, csr, hNb, out, n);
}